// Round 3
// baseline (97.208 us; speedup 1.0000x reference)
//
#include <hip/hip_runtime.h>

// Render_78907139162146: z-buffered triangle rasterizer, 256 tris -> 256x256 RGBA,
// bilinear sample from 3x1024x1024 uvmap.
//
// Scan semantics reduce per-pixel to: winner = last triangle (index order) with
// inside && z >= running max, zbuf init = global min vertex z. Merge is
// associative over index-ordered chunks (later chunk wins ties via >=).
//
// R3 structure: prep kernel writes wave-uniform 24-float triangle records +
// zmin into d_ws; render kernel indexes them with a SCALAR loop variable
// (chunk id via readfirstlane) so record fetches become s_load through the
// constant cache -- no LDS traffic in the hot loop. invalid triangles get
// zeroed edge coefficients (prod==0 -> never inside).
//
// Bit-exactness vs numpy reference: no FMA contraction, exact op order,
// float64-internal linspace (np.linspace computes f64 then casts f32).

#define S 256
#define TMAX 256
#define NC 4      // triangle chunks per block
#define BT 1024   // threads per block (16 waves)
#define RECF 24   // floats per record

__global__ __launch_bounds__(256) void prep_kernel(
    const float* __restrict__ tris,
    const float* __restrict__ uvs,
    float* __restrict__ rec,
    int T)
{
#pragma clang fp contract(off)
    __shared__ float zred[256];
    const int t = threadIdx.x;
    float zl = 3.0e38f;
    if (t < T) {
        const float* p = tris + t * 9;
        float Ax = p[0], Ay = p[1], Az = p[2];
        float Bx = p[3], By = p[4], Bz = p[5];
        float Cx = p[6], Cy = p[7], Cz = p[8];
        float w = (Bx - Ax) * (Cy - Ay) - (By - Ay) * (Cx - Ax);
        bool valid = (w >= 1e-9f);
        const float* q = uvs + t * 6;
        float4* r = (float4*)(rec + t * RECF);
        if (valid) {
            r[0] = make_float4(Bx, By, Ay - By, Ax - Bx);  // pAB = (px-Bx)*z - (py-By)*w
            r[1] = make_float4(Cx, Cy, By - Cy, Bx - Cx);  // pCB
            r[2] = make_float4(Ax, Ay, Cy - Ay, Cx - Ax);  // pCA
        } else {
            r[0] = make_float4(0.f, 0.f, 0.f, 0.f);        // prod==0 -> never inside
            r[1] = make_float4(0.f, 0.f, 0.f, 0.f);
            r[2] = make_float4(0.f, 0.f, 0.f, 0.f);
        }
        r[3] = make_float4(valid ? w : 1.0f, Az, Bz, Cz);
        r[4] = make_float4(q[0] * 2.0f - 1.0f, q[1] * 2.0f - 1.0f,
                           q[2] * 2.0f - 1.0f, q[3] * 2.0f - 1.0f);  // u0x,u0y,u1x,u1y
        r[5] = make_float4(q[4] * 2.0f - 1.0f, q[5] * 2.0f - 1.0f, 0.f, 0.f); // u2x,u2y
        zl = fminf(zl, fminf(Az, fminf(Bz, Cz)));
    }
    zred[t] = zl;
    __syncthreads();
    for (int s = 128; s > 0; s >>= 1) {
        if (t < s) zred[t] = fminf(zred[t], zred[t + s]);
        __syncthreads();
    }
    if (t == 0) rec[TMAX * RECF] = zred[0];
}

__global__ __launch_bounds__(BT) void render_kernel(
    const float* __restrict__ rec,
    const float* __restrict__ uvmap,
    float* __restrict__ out,
    int T)
{
#pragma clang fp contract(off)
    __shared__ float4 cand[NC][S];   // z, w1, w2, win

    const int tid = threadIdx.x;
    const int i = blockIdx.x;                                   // output row
    const int c = __builtin_amdgcn_readfirstlane(tid >> 8);     // chunk, wave-uniform -> SGPR
    const int j = tid & (S - 1);                                // output col

    const float zmin = rec[TMAX * RECF];  // uniform scalar load

    // pts[i,j] = (lin[j], lin[255-i]); np.linspace computes f64, casts f32.
    const float px = (float)(-1.0 + (double)j * (2.0 / 255.0));
    const float py = (float)(-1.0 + (double)(S - 1 - i) * (2.0 / 255.0));

    const int cs   = (T + NC - 1) / NC;
    const int tbeg = c * cs;
    const int tend = (tbeg + cs < T) ? (tbeg + cs) : T;

    float zcur = zmin;
    int win = -1;
    float w1w = 0.0f, w2w = 0.0f;

    for (int t = tbeg; t < tend; ++t) {
        const float4* r = (const float4*)(rec + t * RECF);  // scalar address -> s_load
        float4 r0 = r[0];
        float4 r1 = r[1];
        float4 r2 = r[2];
        float4 r3 = r[3];
        float pAB = (px - r0.x) * r0.z - (py - r0.y) * r0.w;
        float pCB = (px - r1.x) * r1.z - (py - r1.y) * r1.w;
        float pCA = (px - r2.x) * r2.z - (py - r2.y) * r2.w;
        float prod = fmaxf(pAB, 0.0f) * fmaxf(pCB, 0.0f) * fmaxf(pCA, 0.0f);
        if (prod > 0.0f) {
            float w1 = pCB / r3.x;
            float w2 = pCA / r3.x;
            float w3 = (1.0f - w1) - w2;
            float z = (w1 * r3.y + w2 * r3.z) + w3 * r3.w;
            if (z >= zcur) { zcur = z; win = t; w1w = w1; w2w = w2; }
        }
    }
    cand[c][j] = make_float4(zcur, w1w, w2w, (float)win);
    __syncthreads();

    // ---- merge chunk candidates (chunk order = triangle order, >= = later wins) ----
    if (tid < S) {
        float zb = 0.0f, w1 = 0.0f, w2 = 0.0f;
        int w = -1;
        #pragma unroll
        for (int k = 0; k < NC; ++k) {
            float4 ck = cand[k][tid];
            int cw = (int)ck.w;
            if (cw >= 0 && (w < 0 || ck.x >= zb)) {
                zb = ck.x; w1 = ck.y; w2 = ck.z; w = cw;
            }
        }

        // ---- epilogue: bilinear texture sample for the winning triangle ----
        float r = 0.0f, g = 0.0f, b = 0.0f, a = 0.0f;
        if (w >= 0) {
            a = 1.0f;
            float w3 = (1.0f - w1) - w2;
            const float4* rw = (const float4*)(rec + w * RECF);  // divergent -> vector load
            float4 r4 = rw[4];
            float4 r5 = rw[5];
            float ux = (w1 * r4.x + w2 * r4.z) + w3 * r5.x;
            float uy = (w1 * r4.y + w2 * r4.w) + w3 * r5.y;
            float X = ((ux + 1.0f) * 0.5f) * 1023.0f;
            float Y = ((uy + 1.0f) * 0.5f) * 1023.0f;
            float x0 = floorf(X), y0 = floorf(Y);
            float wx = X - x0, wy = Y - y0;
            float w00 = (1.0f - wx) * (1.0f - wy);
            float w10 = wx * (1.0f - wy);
            float w01 = (1.0f - wx) * wy;
            float w11 = wx * wy;
            float xs1 = x0 + 1.0f, ys1 = y0 + 1.0f;
            bool xin0 = (x0  >= 0.0f) && (x0  <= 1023.0f);
            bool xin1 = (xs1 >= 0.0f) && (xs1 <= 1023.0f);
            bool yin0 = (y0  >= 0.0f) && (y0  <= 1023.0f);
            bool yin1 = (ys1 >= 0.0f) && (ys1 <= 1023.0f);
            int xi0 = (int)fminf(fmaxf(x0,  0.0f), 1023.0f);
            int xi1 = (int)fminf(fmaxf(xs1, 0.0f), 1023.0f);
            int yi0 = (int)fminf(fmaxf(y0,  0.0f), 1023.0f);
            int yi1 = (int)fminf(fmaxf(ys1, 0.0f), 1023.0f);
            float acc[3];
            #pragma unroll
            for (int ch = 0; ch < 3; ++ch) {
                const float* img = uvmap + ch * (1024 * 1024);
                float v00 = (xin0 && yin0) ? img[yi0 * 1024 + xi0] : 0.0f;
                float v10 = (xin1 && yin0) ? img[yi0 * 1024 + xi1] : 0.0f;
                float v01 = (xin0 && yin1) ? img[yi1 * 1024 + xi0] : 0.0f;
                float v11 = (xin1 && yin1) ? img[yi1 * 1024 + xi1] : 0.0f;
                acc[ch] = ((v00 * w00 + v10 * w10) + v01 * w01) + v11 * w11;
            }
            r = acc[0]; g = acc[1]; b = acc[2];
        }

        const int base = i * S + tid;
        out[0 * S * S + base] = r;
        out[1 * S * S + base] = g;
        out[2 * S * S + base] = b;
        out[3 * S * S + base] = a;
    }
}

extern "C" void kernel_launch(void* const* d_in, const int* in_sizes, int n_in,
                              void* d_out, int out_size, void* d_ws, size_t ws_size,
                              hipStream_t stream) {
    const float* tris  = (const float*)d_in[0];
    const float* uvs   = (const float*)d_in[1];
    const float* uvmap = (const float*)d_in[2];
    float* out = (float*)d_out;
    float* rec = (float*)d_ws;   // TMAX*RECF floats + 1 zmin
    int T = in_sizes[0] / 9;
    if (T > TMAX) T = TMAX;
    prep_kernel<<<dim3(1), dim3(256), 0, stream>>>(tris, uvs, rec, T);
    render_kernel<<<dim3(S), dim3(BT), 0, stream>>>(rec, uvmap, out, T);
}

// Round 4
// 78.269 us; speedup vs baseline: 1.2420x; 1.2420x over previous
//
#include <hip/hip_runtime.h>

// Render_78907139162146: z-buffered triangle rasterizer, 256 tris -> 256x256 RGBA,
// bilinear sample from 3x1024x1024 uvmap.
//
// Scan semantics reduce per-pixel to: winner = last argmax of z (>= zmin, ties ->
// later index), zmin = global min vertex z. Associative over index-ordered
// chunks (later chunk wins ties via >=).
//
// R4: single kernel (R3's 2-launch split cost more than it saved). Grid 512 =
// 2 half-row blocks/CU -> 8 waves/SIMD (vs 4). Per-row y-bbox culling with
// order-preserving ballot compaction halves the live-triangle list; margin
// 0.02 >> ~3e-6 float edge-function rounding bound, so culled tris provably
// can't be float-inside for this row (non-sliver w >= ~1e-3 in this input).
//
// Bit-exactness for survivors: no FMA contraction, exact op order,
// float64-internal linspace (np.linspace computes f64 then casts f32).

#define S 256
#define TMAX 256
#define NC 8       // triangle chunks per block
#define BT 1024    // threads per block (16 waves)
#define HALF 128   // pixels per block (half row)
#define MARGIN 0.02f

__global__ __launch_bounds__(BT) void render_kernel(
    const float* __restrict__ tris,
    const float* __restrict__ uvs,
    const float* __restrict__ uvmap,
    float* __restrict__ out,
    int T)
{
#pragma clang fp contract(off)
    // Per-triangle record, 4 x float4 (hot-loop part only; uvs read in epilogue):
    //  r0: Bx, By, (Ay-By), (Ax-Bx)    -> pAB = (px-Bx)*r0.z - (py-By)*r0.w
    //  r1: Cx, Cy, (By-Cy), (Bx-Cx)    -> pCB
    //  r2: Ax, Ay, (Cy-Ay), (Cx-Ax)    -> pCA
    //  r3: ws, Az, Bz, Cz
    __shared__ float4 sd[TMAX][4];
    __shared__ float  zred[TMAX];
    __shared__ int    list[TMAX];
    __shared__ unsigned long long masks[4];
    __shared__ int    woff[5];
    __shared__ float4 cand[NC][HALF];   // z, w1, w2, win

    const int tid  = threadIdx.x;
    const int bid  = blockIdx.x;
    const int row  = bid >> 1;          // output row
    const int half = bid & 1;           // which half of the row
    const int j    = half * HALF + (tid & (HALF - 1));   // output col
    const int c    = tid >> 7;          // chunk 0..7 (uniform per wave)

    // pts[row,j] = (lin[j], lin[255-row]); np.linspace computes f64, casts f32.
    const float px = (float)(-1.0 + (double)j * (2.0 / 255.0));
    const float py = (float)(-1.0 + (double)(S - 1 - row) * (2.0 / 255.0));

    // ---- stage records, per-triangle zmin, y-cull flag ----
    bool keep = false;
    if (tid < TMAX) {
        if (tid < T) {
            const float* p = tris + tid * 9;
            float Ax = p[0], Ay = p[1], Az = p[2];
            float Bx = p[3], By = p[4], Bz = p[5];
            float Cx = p[6], Cy = p[7], Cz = p[8];
            float w = (Bx - Ax) * (Cy - Ay) - (By - Ay) * (Cx - Ax);
            bool valid = (w >= 1e-9f);
            sd[tid][0] = make_float4(Bx, By, Ay - By, Ax - Bx);
            sd[tid][1] = make_float4(Cx, Cy, By - Cy, Bx - Cx);
            sd[tid][2] = make_float4(Ax, Ay, Cy - Ay, Cx - Ax);
            sd[tid][3] = make_float4(valid ? w : 1.0f, Az, Bz, Cz);
            zred[tid] = fminf(Az, fminf(Bz, Cz));
            float ymn = fminf(Ay, fminf(By, Cy));
            float ymx = fmaxf(Ay, fmaxf(By, Cy));
            keep = valid && (py >= ymn - MARGIN) && (py <= ymx + MARGIN);
        } else {
            zred[tid] = 3.0e38f;
        }
    }
    unsigned long long m = __ballot(keep);
    if (tid < TMAX && (tid & 63) == 0) masks[tid >> 6] = m;
    __syncthreads();

    // prefix totals (thread 512, outside the zmin tree) + zmin tree over 256
    if (tid == 512) {
        int s = 0;
        #pragma unroll
        for (int k = 0; k < 4; ++k) { woff[k] = s; s += __popcll(masks[k]); }
        woff[4] = s;
    }
    for (int s = TMAX / 2; s > 0; s >>= 1) {
        if (tid < s) zred[tid] = fminf(zred[tid], zred[tid + s]);
        __syncthreads();
    }
    // order-preserving compaction
    if (tid < TMAX && keep) {
        int lane = tid & 63;
        int wv   = tid >> 6;
        int pos  = woff[wv] + __popcll(masks[wv] & ((1ull << lane) - 1ull));
        list[pos] = tid;
    }
    __syncthreads();

    const float zmin  = zred[0];
    const int   nlive = woff[4];

    // ---- per-pixel rasterization over this chunk's slice of the live list ----
    const int cs = (nlive + NC - 1) / NC;
    const int tb = c * cs;
    const int te = (tb + cs < nlive) ? (tb + cs) : nlive;

    float zcur = zmin;
    int win = -1;
    float w1w = 0.0f, w2w = 0.0f;

    for (int it = tb; it < te; ++it) {
        int tt = list[it];                       // uniform -> broadcast ds_read
        float4 r0 = sd[tt][0];
        float4 r1 = sd[tt][1];
        float4 r2 = sd[tt][2];
        float4 r3 = sd[tt][3];
        float pAB = (px - r0.x) * r0.z - (py - r0.y) * r0.w;
        float pCB = (px - r1.x) * r1.z - (py - r1.y) * r1.w;
        float pCA = (px - r2.x) * r2.z - (py - r2.y) * r2.w;
        float prod = fmaxf(pAB, 0.0f) * fmaxf(pCB, 0.0f) * fmaxf(pCA, 0.0f);
        if (prod > 0.0f) {
            float w1 = pCB / r3.x;
            float w2 = pCA / r3.x;
            float w3 = (1.0f - w1) - w2;
            float z = (w1 * r3.y + w2 * r3.z) + w3 * r3.w;
            if (z >= zcur) { zcur = z; win = tt; w1w = w1; w2w = w2; }
        }
    }
    cand[c][tid & (HALF - 1)] = make_float4(zcur, w1w, w2w, (float)win);
    __syncthreads();

    // ---- merge chunk candidates (ascending chunk = ascending tri index; >= = later wins) ----
    if (tid < HALF) {
        float zb = 0.0f, w1 = 0.0f, w2 = 0.0f;
        int w = -1;
        #pragma unroll
        for (int k = 0; k < NC; ++k) {
            float4 ck = cand[k][tid];
            int cw = (int)ck.w;
            if (cw >= 0 && (w < 0 || ck.x >= zb)) {
                zb = ck.x; w1 = ck.y; w2 = ck.z; w = cw;
            }
        }

        // ---- epilogue: bilinear texture sample for the winning triangle ----
        float r = 0.0f, g = 0.0f, b = 0.0f, a = 0.0f;
        if (w >= 0) {
            a = 1.0f;
            float w3 = (1.0f - w1) - w2;
            const float* q = uvs + w * 6;        // divergent winner -> vector loads
            float u0x = q[0] * 2.0f - 1.0f, u0y = q[1] * 2.0f - 1.0f;
            float u1x = q[2] * 2.0f - 1.0f, u1y = q[3] * 2.0f - 1.0f;
            float u2x = q[4] * 2.0f - 1.0f, u2y = q[5] * 2.0f - 1.0f;
            float ux = (w1 * u0x + w2 * u1x) + w3 * u2x;
            float uy = (w1 * u0y + w2 * u1y) + w3 * u2y;
            float X = ((ux + 1.0f) * 0.5f) * 1023.0f;
            float Y = ((uy + 1.0f) * 0.5f) * 1023.0f;
            float x0 = floorf(X), y0 = floorf(Y);
            float wx = X - x0, wy = Y - y0;
            float w00 = (1.0f - wx) * (1.0f - wy);
            float w10 = wx * (1.0f - wy);
            float w01 = (1.0f - wx) * wy;
            float w11 = wx * wy;
            float xs1 = x0 + 1.0f, ys1 = y0 + 1.0f;
            bool xin0 = (x0  >= 0.0f) && (x0  <= 1023.0f);
            bool xin1 = (xs1 >= 0.0f) && (xs1 <= 1023.0f);
            bool yin0 = (y0  >= 0.0f) && (y0  <= 1023.0f);
            bool yin1 = (ys1 >= 0.0f) && (ys1 <= 1023.0f);
            int xi0 = (int)fminf(fmaxf(x0,  0.0f), 1023.0f);
            int xi1 = (int)fminf(fmaxf(xs1, 0.0f), 1023.0f);
            int yi0 = (int)fminf(fmaxf(y0,  0.0f), 1023.0f);
            int yi1 = (int)fminf(fmaxf(ys1, 0.0f), 1023.0f);
            float acc[3];
            #pragma unroll
            for (int ch = 0; ch < 3; ++ch) {
                const float* img = uvmap + ch * (1024 * 1024);
                float v00 = (xin0 && yin0) ? img[yi0 * 1024 + xi0] : 0.0f;
                float v10 = (xin1 && yin0) ? img[yi0 * 1024 + xi1] : 0.0f;
                float v01 = (xin0 && yin1) ? img[yi1 * 1024 + xi0] : 0.0f;
                float v11 = (xin1 && yin1) ? img[yi1 * 1024 + xi1] : 0.0f;
                acc[ch] = ((v00 * w00 + v10 * w10) + v01 * w01) + v11 * w11;
            }
            r = acc[0]; g = acc[1]; b = acc[2];
        }

        const int base = row * S + j;
        out[0 * S * S + base] = r;
        out[1 * S * S + base] = g;
        out[2 * S * S + base] = b;
        out[3 * S * S + base] = a;
    }
}

extern "C" void kernel_launch(void* const* d_in, const int* in_sizes, int n_in,
                              void* d_out, int out_size, void* d_ws, size_t ws_size,
                              hipStream_t stream) {
    const float* tris  = (const float*)d_in[0];
    const float* uvs   = (const float*)d_in[1];
    const float* uvmap = (const float*)d_in[2];
    float* out = (float*)d_out;
    int T = in_sizes[0] / 9;
    if (T > TMAX) T = TMAX;
    render_kernel<<<dim3(2 * S), dim3(BT), 0, stream>>>(tris, uvs, uvmap, out, T);
}

// Round 5
// 76.780 us; speedup vs baseline: 1.2661x; 1.0194x over previous
//
#include <hip/hip_runtime.h>

// Render_78907139162146: z-buffered triangle rasterizer, 256 tris -> 256x256 RGBA,
// bilinear sample from 3x1024x1024 uvmap.
//
// Scan semantics reduce per-pixel to: winner = last argmax of z (>= zmin, ties ->
// later index), zmin = global min vertex z. Associative over index-ordered
// chunks (later chunk wins ties via >=).
//
// R5: (a) zmin via per-wave __shfl_xor reduce + single LDS combine -- block
// barrier count ~12 -> 3 (the 8-barrier tree was ~10% of kernel time at 16
// waves/block); (b) x-bbox cull in addition to y-cull: block = half-row, x
// window = 1.0 NDC; cull margin 0.02 >> ~3e-6 float edge-function rounding
// bound, so culled tris provably can't be float-inside for this block's pixels.
//
// Bit-exactness for survivors: no FMA contraction, exact op order,
// float64-internal linspace (np.linspace computes f64, casts f32). fmin-based
// zmin is exact in any order.

#define S 256
#define TMAX 256
#define NC 8       // triangle chunks per block
#define BT 1024    // threads per block (16 waves)
#define HALF 128   // pixels per block (half row)
#define MARGIN 0.02f

__global__ __launch_bounds__(BT) void render_kernel(
    const float* __restrict__ tris,
    const float* __restrict__ uvs,
    const float* __restrict__ uvmap,
    float* __restrict__ out,
    int T)
{
#pragma clang fp contract(off)
    // Per-triangle record, 4 x float4 (hot-loop part; uvs read in epilogue):
    //  r0: Bx, By, (Ay-By), (Ax-Bx)    -> pAB = (px-Bx)*r0.z - (py-By)*r0.w
    //  r1: Cx, Cy, (By-Cy), (Bx-Cx)    -> pCB
    //  r2: Ax, Ay, (Cy-Ay), (Cx-Ax)    -> pCA
    //  r3: ws, Az, Bz, Cz
    __shared__ float4 sd[TMAX][4];
    __shared__ int    list[TMAX];
    __shared__ unsigned long long masks[4];
    __shared__ float  zpart[4];
    __shared__ float4 cand[NC][HALF];   // z, w1, w2, win

    const int tid  = threadIdx.x;
    const int bid  = blockIdx.x;
    const int row  = bid >> 1;          // output row
    const int half = bid & 1;           // which half of the row
    const int j    = half * HALF + (tid & (HALF - 1));   // output col
    const int c    = tid >> 7;          // chunk 0..7 (uniform per wave)

    // pts[row,j] = (lin[j], lin[255-row]); np.linspace computes f64, casts f32.
    const float px = (float)(-1.0 + (double)j * (2.0 / 255.0));
    const float py = (float)(-1.0 + (double)(S - 1 - row) * (2.0 / 255.0));
    // block x-window (inclusive pixel extremes of this half-row)
    const float pxlo = (float)(-1.0 + (double)(half * HALF) * (2.0 / 255.0));
    const float pxhi = (float)(-1.0 + (double)(half * HALF + HALF - 1) * (2.0 / 255.0));

    // ---- stage records, cull flag, per-wave zmin (waves 0..3) ----
    bool keep = false;
    float zl = 3.0e38f;
    if (tid < TMAX && tid < T) {
        const float* p = tris + tid * 9;
        float Ax = p[0], Ay = p[1], Az = p[2];
        float Bx = p[3], By = p[4], Bz = p[5];
        float Cx = p[6], Cy = p[7], Cz = p[8];
        float w = (Bx - Ax) * (Cy - Ay) - (By - Ay) * (Cx - Ax);
        bool valid = (w >= 1e-9f);
        sd[tid][0] = make_float4(Bx, By, Ay - By, Ax - Bx);
        sd[tid][1] = make_float4(Cx, Cy, By - Cy, Bx - Cx);
        sd[tid][2] = make_float4(Ax, Ay, Cy - Ay, Cx - Ax);
        sd[tid][3] = make_float4(valid ? w : 1.0f, Az, Bz, Cz);
        zl = fminf(Az, fminf(Bz, Cz));
        float ymn = fminf(Ay, fminf(By, Cy));
        float ymx = fmaxf(Ay, fmaxf(By, Cy));
        float xmn = fminf(Ax, fminf(Bx, Cx));
        float xmx = fmaxf(Ax, fmaxf(Bx, Cx));
        keep = valid && (py >= ymn - MARGIN) && (py <= ymx + MARGIN)
                     && (pxhi >= xmn - MARGIN) && (pxlo <= xmx + MARGIN);
    }
    unsigned long long m = __ballot(keep);
    if (tid < TMAX) {
        float zw = zl;
        #pragma unroll
        for (int o = 32; o > 0; o >>= 1) zw = fminf(zw, __shfl_xor(zw, o, 64));
        if ((tid & 63) == 0) { masks[tid >> 6] = m; zpart[tid >> 6] = zw; }
    }
    __syncthreads();   // barrier 1: masks, zpart, sd visible

    // every thread computes prefix offsets locally (4 popcnts, no barrier)
    int n0 = __popcll(masks[0]);
    int n1 = __popcll(masks[1]);
    int n2 = __popcll(masks[2]);
    int n3 = __popcll(masks[3]);
    const int nlive = n0 + n1 + n2 + n3;
    const float zmin = fminf(fminf(zpart[0], zpart[1]), fminf(zpart[2], zpart[3]));

    // order-preserving compaction (waves 0..3)
    if (tid < TMAX && keep) {
        int lane = tid & 63;
        int wv   = tid >> 6;
        int off  = (wv > 0 ? n0 : 0) + (wv > 1 ? n1 : 0) + (wv > 2 ? n2 : 0);
        int pos  = off + __popcll(masks[wv] & ((1ull << lane) - 1ull));
        list[pos] = tid;
    }
    __syncthreads();   // barrier 2: list visible

    // ---- per-pixel rasterization over this chunk's slice of the live list ----
    const int cs = (nlive + NC - 1) / NC;
    const int tb = c * cs;
    const int te = (tb + cs < nlive) ? (tb + cs) : nlive;

    float zcur = zmin;
    int win = -1;
    float w1w = 0.0f, w2w = 0.0f;

    for (int it = tb; it < te; ++it) {
        int tt = list[it];                       // uniform -> broadcast ds_read
        float4 r0 = sd[tt][0];
        float4 r1 = sd[tt][1];
        float4 r2 = sd[tt][2];
        float4 r3 = sd[tt][3];
        float pAB = (px - r0.x) * r0.z - (py - r0.y) * r0.w;
        float pCB = (px - r1.x) * r1.z - (py - r1.y) * r1.w;
        float pCA = (px - r2.x) * r2.z - (py - r2.y) * r2.w;
        float prod = fmaxf(pAB, 0.0f) * fmaxf(pCB, 0.0f) * fmaxf(pCA, 0.0f);
        if (prod > 0.0f) {
            float w1 = pCB / r3.x;
            float w2 = pCA / r3.x;
            float w3 = (1.0f - w1) - w2;
            float z = (w1 * r3.y + w2 * r3.z) + w3 * r3.w;
            if (z >= zcur) { zcur = z; win = tt; w1w = w1; w2w = w2; }
        }
    }
    cand[c][tid & (HALF - 1)] = make_float4(zcur, w1w, w2w, (float)win);
    __syncthreads();   // barrier 3: cand visible

    // ---- merge chunk candidates (ascending chunk = ascending tri index; >= = later wins) ----
    if (tid < HALF) {
        float zb = 0.0f, w1 = 0.0f, w2 = 0.0f;
        int w = -1;
        #pragma unroll
        for (int k = 0; k < NC; ++k) {
            float4 ck = cand[k][tid];
            int cw = (int)ck.w;
            if (cw >= 0 && (w < 0 || ck.x >= zb)) {
                zb = ck.x; w1 = ck.y; w2 = ck.z; w = cw;
            }
        }

        // ---- epilogue: bilinear texture sample for the winning triangle ----
        float r = 0.0f, g = 0.0f, b = 0.0f, a = 0.0f;
        if (w >= 0) {
            a = 1.0f;
            float w3 = (1.0f - w1) - w2;
            const float* q = uvs + w * 6;        // divergent winner -> vector loads
            float u0x = q[0] * 2.0f - 1.0f, u0y = q[1] * 2.0f - 1.0f;
            float u1x = q[2] * 2.0f - 1.0f, u1y = q[3] * 2.0f - 1.0f;
            float u2x = q[4] * 2.0f - 1.0f, u2y = q[5] * 2.0f - 1.0f;
            float ux = (w1 * u0x + w2 * u1x) + w3 * u2x;
            float uy = (w1 * u0y + w2 * u1y) + w3 * u2y;
            float X = ((ux + 1.0f) * 0.5f) * 1023.0f;
            float Y = ((uy + 1.0f) * 0.5f) * 1023.0f;
            float x0 = floorf(X), y0 = floorf(Y);
            float wx = X - x0, wy = Y - y0;
            float w00 = (1.0f - wx) * (1.0f - wy);
            float w10 = wx * (1.0f - wy);
            float w01 = (1.0f - wx) * wy;
            float w11 = wx * wy;
            float xs1 = x0 + 1.0f, ys1 = y0 + 1.0f;
            bool xin0 = (x0  >= 0.0f) && (x0  <= 1023.0f);
            bool xin1 = (xs1 >= 0.0f) && (xs1 <= 1023.0f);
            bool yin0 = (y0  >= 0.0f) && (y0  <= 1023.0f);
            bool yin1 = (ys1 >= 0.0f) && (ys1 <= 1023.0f);
            int xi0 = (int)fminf(fmaxf(x0,  0.0f), 1023.0f);
            int xi1 = (int)fminf(fmaxf(xs1, 0.0f), 1023.0f);
            int yi0 = (int)fminf(fmaxf(y0,  0.0f), 1023.0f);
            int yi1 = (int)fminf(fmaxf(ys1, 0.0f), 1023.0f);
            float acc[3];
            #pragma unroll
            for (int ch = 0; ch < 3; ++ch) {
                const float* img = uvmap + ch * (1024 * 1024);
                float v00 = (xin0 && yin0) ? img[yi0 * 1024 + xi0] : 0.0f;
                float v10 = (xin1 && yin0) ? img[yi0 * 1024 + xi1] : 0.0f;
                float v01 = (xin0 && yin1) ? img[yi1 * 1024 + xi0] : 0.0f;
                float v11 = (xin1 && yin1) ? img[yi1 * 1024 + xi1] : 0.0f;
                acc[ch] = ((v00 * w00 + v10 * w10) + v01 * w01) + v11 * w11;
            }
            r = acc[0]; g = acc[1]; b = acc[2];
        }

        const int base = row * S + j;
        out[0 * S * S + base] = r;
        out[1 * S * S + base] = g;
        out[2 * S * S + base] = b;
        out[3 * S * S + base] = a;
    }
}

extern "C" void kernel_launch(void* const* d_in, const int* in_sizes, int n_in,
                              void* d_out, int out_size, void* d_ws, size_t ws_size,
                              hipStream_t stream) {
    const float* tris  = (const float*)d_in[0];
    const float* uvs   = (const float*)d_in[1];
    const float* uvmap = (const float*)d_in[2];
    float* out = (float*)d_out;
    int T = in_sizes[0] / 9;
    if (T > TMAX) T = TMAX;
    render_kernel<<<dim3(2 * S), dim3(BT), 0, stream>>>(tris, uvs, uvmap, out, T);
}